// Round 9
// baseline (319.079 us; speedup 1.0000x reference)
//
#include <hip/hip_runtime.h>
#include <math.h>

#define DM 1024
#define DF 1024
#define NE 8
#define NBIN 16          // (pass, expert) bins: bin = p*8 + e
#define MAXT 136         // max worklist tiles per pass
#define BM 128
#define BN 128
#define BKT 32
#define NT 32            // K-steps = DM/BKT

typedef __bf16 bf16x8 __attribute__((ext_vector_type(8)));
typedef __bf16 bf16x4 __attribute__((ext_vector_type(4)));
typedef float floatx4 __attribute__((ext_vector_type(4)));

typedef const __attribute__((address_space(1))) unsigned int* gas_t;
typedef __attribute__((address_space(3))) unsigned int* las_t;

__device__ __forceinline__ void ld_lds16(const void* g, void* l) {
    __builtin_amdgcn_global_load_lds((gas_t)g, (las_t)l, 16, 0, 0);
}

#define WAITVM(N) asm volatile("s_waitcnt vmcnt(" #N ")" ::: "memory")
#define SCHEDB()  __builtin_amdgcn_sched_barrier(0)
#define BARRIER() do { asm volatile("" ::: "memory"); \
                       __builtin_amdgcn_s_barrier(); \
                       asm volatile("" ::: "memory"); } while (0)

// ---------------- ws layout ----------------
// [0, 33.5M)      Xb   bf16[T][1024]
// [33.5M, 50.3M)  WeT  bf16[8][1024][1024]  ([e][n][k])
// [50.3M, ...)    routing: ntiles[2], wl0/wl1 (int4[136] each), blk_cnt, blk_base,
//                 tok_e, tok_w, gath_tok, gath_w

__global__ void convert_weT(const float* __restrict__ We, __bf16* __restrict__ WeT) {
    int n  = blockIdx.x * 256 + threadIdx.x;
    int kc = blockIdx.y * 8;
    int e  = blockIdx.z;
    const float* src = We + ((size_t)e << 20) + (size_t)kc * DF + n;
    bf16x8 v;
#pragma unroll
    for (int j = 0; j < 8; ++j) v[j] = (__bf16)src[(size_t)j * DF];
    *(bf16x8*)&WeT[((size_t)e << 20) + (size_t)n * DM + kc] = v;
}

// fused: gate logits + top-2 + sigmoid + X -> bf16 conversion (X already in regs)
__global__ void gate_kernel(const float4* __restrict__ X4, const float4* __restrict__ Wg4,
                            const float* __restrict__ bg, int* __restrict__ tok_e,
                            float* __restrict__ tok_w, __bf16* __restrict__ Xb, int T) {
    int wid  = threadIdx.x >> 6;
    int lane = threadIdx.x & 63;
    int t = blockIdx.x * 4 + wid;
    if (t >= T) return;
    float acc[NE] = {};
    float4 xs[4];
#pragma unroll
    for (int c = 0; c < 4; ++c) {
        float4 xv = X4[(size_t)t * 256 + c * 64 + lane];
        xs[c] = xv;
#pragma unroll
        for (int e = 0; e < NE; ++e) {
            float4 wv = Wg4[e * 256 + c * 64 + lane];
            acc[e] += xv.x * wv.x + xv.y * wv.y + xv.z * wv.z + xv.w * wv.w;
        }
    }
    // convert this token's X row to bf16 (coalesced 8B stores)
#pragma unroll
    for (int c = 0; c < 4; ++c) {
        bf16x4 v;
        v[0] = (__bf16)xs[c].x; v[1] = (__bf16)xs[c].y;
        v[2] = (__bf16)xs[c].z; v[3] = (__bf16)xs[c].w;
        *(bf16x4*)&Xb[(size_t)t * DM + c * 256 + lane * 4] = v;
    }
#pragma unroll
    for (int e = 0; e < NE; ++e) {
#pragma unroll
        for (int off = 32; off > 0; off >>= 1)
            acc[e] += __shfl_down(acc[e], off, 64);
    }
    if (lane == 0) {
        float l[NE];
#pragma unroll
        for (int e = 0; e < NE; ++e) l[e] = acc[e] + bg[e];
        int b0 = 0; float v0 = l[0];
        for (int e = 1; e < NE; ++e) if (l[e] > v0) { v0 = l[e]; b0 = e; }
        int b1 = -1; float v1 = -3.4e38f;
        for (int e = 0; e < NE; ++e) if (e != b0 && l[e] > v1) { v1 = l[e]; b1 = e; }
        tok_e[2 * t]     = b0;  tok_e[2 * t + 1] = b1;
        tok_w[2 * t]     = 1.f / (1.f + expf(-v0));
        tok_w[2 * t + 1] = 1.f / (1.f + expf(-v1));
    }
}

// per-block 16-bin histogram via ballots (no global atomics)
__global__ void hist_kernel(const int* __restrict__ tok_e, int* __restrict__ blk_cnt, int n) {
    int b = blockIdx.x, tid = threadIdx.x;
    int idx  = b * 256 + tid;
    int lane = tid & 63, w = tid >> 6;
    int bin = (idx < n) ? ((idx & 1) * NE + tok_e[idx]) : -1;
    __shared__ int wc[4][NBIN];
#pragma unroll
    for (int bx = 0; bx < NBIN; ++bx) {
        unsigned long long m = __ballot(bin == bx);
        if (lane == 0) wc[w][bx] = (int)__popcll(m);
    }
    __syncthreads();
    if (tid < NBIN) blk_cnt[b * NBIN + tid] = wc[0][tid] + wc[1][tid] + wc[2][tid] + wc[3][tid];
}

// scan over blocks + bins, and build the two GEMM worklists
__global__ void scan_kernel(const int* __restrict__ blk_cnt, int* __restrict__ blk_base,
                            int4* __restrict__ wl, int* __restrict__ ntiles, int NB) {
    __shared__ int c[2048];
    __shared__ int tot[NBIN], base[NBIN];
    int tid = threadIdx.x;
    for (int i = tid; i < NB * NBIN; i += 256) c[i] = blk_cnt[i];
    __syncthreads();
    if (tid < NBIN) {
        int s = 0;
        for (int b = 0; b < NB; ++b) s += c[b * NBIN + tid];
        tot[tid] = s;
    }
    __syncthreads();
    if (tid == 0) {
        int s = 0;
        for (int b = 0; b < NBIN; ++b) { base[b] = s; s += tot[b]; }
    }
    __syncthreads();
    if (tid < NBIN) {
        int run = base[tid];
        for (int b = 0; b < NB; ++b) { int v = c[b * NBIN + tid]; c[b * NBIN + tid] = run; run += v; }
    }
    __syncthreads();
    for (int i = tid; i < NB * NBIN; i += 256) blk_base[i] = c[i];
    if (tid == 0) {
        for (int p = 0; p < 2; ++p) {
            int nt = 0;
            for (int e = 0; e < NE; ++e) {
                int bin = p * NE + e;
                int cnt = tot[bin], sg = base[bin];
                for (int r0 = 0; r0 < cnt; r0 += BM)
                    wl[p * MAXT + nt++] = make_int4(e, r0, sg, cnt);
            }
            ntiles[p] = nt;
        }
    }
}

// deterministic rank-based scatter into 16 bins (no global atomics)
__global__ void scatter_kernel(const int* __restrict__ tok_e, const float* __restrict__ tok_w,
                               const int* __restrict__ blk_base, int* __restrict__ gath_tok,
                               float* __restrict__ gath_w, int n) {
    int b = blockIdx.x, tid = threadIdx.x;
    int idx  = b * 256 + tid;
    int lane = tid & 63, w = tid >> 6;
    bool act = idx < n;
    int bin = act ? ((idx & 1) * NE + tok_e[idx]) : -1;
    __shared__ int wc[4][NBIN], wb[4][NBIN];
    int myrank = 0;
#pragma unroll
    for (int bx = 0; bx < NBIN; ++bx) {
        unsigned long long m = __ballot(bin == bx);
        if (lane == 0) wc[w][bx] = (int)__popcll(m);
        if (bin == bx) myrank = (int)__popcll(m & ((1ull << lane) - 1ull));
    }
    __syncthreads();
    if (tid < NBIN) {
        int run = blk_base[b * NBIN + tid];
#pragma unroll
        for (int wv = 0; wv < 4; ++wv) { wb[wv][tid] = run; run += wc[wv][tid]; }
    }
    __syncthreads();
    if (act) {
        int pos = wb[w][bin] + myrank;
        gath_tok[pos] = idx >> 1;
        gath_w[pos]   = tok_w[idx];
    }
}

// 128x128 tile, wave tile 64x64 (acc[4][4]), BKT=32, 3 staging buffers
// (tile t -> buffer t%3), R6-proven 2-barrier counted-vmcnt schedule:
//   COMP(b); BARRIER; STAGE((b+2)%3, t+2); WAITVM(4); BARRIER;
// Every COMP's tile lands at the immediately preceding WAITVM(4); every STAGE
// is >=2 barriers after its buffer's last readers. 50 KB LDS -> 3 blocks/CU.
// LDS swizzle identical to R6: element (r, kchunk c) at physical chunk
// c ^ ((r%16)>>1 & 3); global source pre-swizzled (rule #21).
template <bool ACC>
__global__ __launch_bounds__(256) void expert_gemm_mfma(
        const __bf16* __restrict__ Xb, const __bf16* __restrict__ WeT,
        const float* __restrict__ be, const int4* __restrict__ wl,
        const int* __restrict__ ntiles, const int* __restrict__ gtok,
        const float* __restrict__ gw, float* __restrict__ out) {
    // chunked XCD swizzle (bijective: 1088 = 8 * 136): XCD k gets 17 consecutive
    // worklist tiles x all 8 col-blocks -> A-rows and B-panels L2-resident per XCD
    int sw = (blockIdx.x & 7) * MAXT + (blockIdx.x >> 3);
    int tix  = sw >> 3;
    int col0 = (sw & 7) * BN;
    if (tix >= ntiles[0]) return;
    int4 ent = wl[tix];
    int e = ent.x, row0 = ent.y, seg = ent.z, n_e = ent.w;

    // 48 KB: 3 buffers x (8 KB A + 8 KB B). Epilogue Cs (128x64 f32 = 32 KB)
    // overlays the buffer region (two column-half rounds).
    __shared__ __align__(16) char smem[49152];
    __bf16* Asb = (__bf16*)smem;               // 3 x 4096 bf16 (8 KB each)
    __bf16* Bsb = (__bf16*)(smem + 24576);     // 3 x 4096 bf16 (8 KB each)
    float*  Cs  = (float*)smem;
    __shared__ int   s_tok[BM];
    __shared__ float s_w[BM];

    int tid = threadIdx.x;
    if (tid < BM) {
        int gr = row0 + tid;
        s_tok[tid] = (gr < n_e) ? gtok[seg + gr] : gtok[seg];
        s_w[tid]   = (gr < n_e) ? gw[seg + gr]   : 0.f;
    }
    __syncthreads();

    int lane = tid & 63, w = tid >> 6;
    int rsub = lane >> 2;                        // 0..15
    int kc   = (lane & 3) ^ ((lane >> 3) & 3);   // pre-swizzled global k-chunk

    // staging rows: A rows {w*16+rsub, 64+w*16+rsub}; B rows same pattern
    const __bf16* aptr0 = Xb + (size_t)s_tok[w * 16 + rsub] * DM + kc * 8;
    const __bf16* aptr1 = Xb + (size_t)s_tok[(4 + w) * 16 + rsub] * DM + kc * 8;
    const __bf16* bptr0 = WeT + ((size_t)e << 20)
                        + (size_t)(col0 + w * 16 + rsub) * DM + kc * 8;
    const __bf16* bptr1 = WeT + ((size_t)e << 20)
                        + (size_t)(col0 + 64 + w * 16 + rsub) * DM + kc * 8;

    int wr  = (w >> 1) * 64;     // wave out-row base
    int wcc = (w & 1) * 64;      // wave out-col base
    int m16 = lane & 15, q4 = lane >> 4;
    int ccu = q4 ^ ((m16 >> 1) & 3);             // physical chunk for LDS reads

    floatx4 acc[4][4] = {};

#define STAGE(B, KS) do { \
    ld_lds16(aptr0 + (KS) * BKT, Asb + (B) * 4096 + w * 512); \
    ld_lds16(aptr1 + (KS) * BKT, Asb + (B) * 4096 + (4 + w) * 512); \
    ld_lds16(bptr0 + (KS) * BKT, Bsb + (B) * 4096 + w * 512); \
    ld_lds16(bptr1 + (KS) * BKT, Bsb + (B) * 4096 + (4 + w) * 512); } while (0)

#define COMP(B) do { \
    bf16x8 af[4], bfr[4]; \
    _Pragma("unroll") \
    for (int i = 0; i < 4; ++i) \
        af[i] = *(const bf16x8*)&Asb[(B) * 4096 + (wr + i * 16 + m16) * 32 + ccu * 8]; \
    _Pragma("unroll") \
    for (int j = 0; j < 4; ++j) \
        bfr[j] = *(const bf16x8*)&Bsb[(B) * 4096 + (wcc + j * 16 + m16) * 32 + ccu * 8]; \
    _Pragma("unroll") \
    for (int i = 0; i < 4; ++i) \
        _Pragma("unroll") \
        for (int j = 0; j < 4; ++j) \
            acc[i][j] = __builtin_amdgcn_mfma_f32_16x16x32_bf16(af[i], bfr[j], acc[i][j], 0, 0, 0); \
    } while (0)

    // prologue: tiles 0,1 in flight; wait tile 0 (oldest 4 of 8 loads)
    STAGE(0, 0); STAGE(1, 1);
    WAITVM(4); SCHEDB();
    BARRIER();

    // steady state (R6 pattern, 3-buffer rotation): computes tiles 0..29,
    // stages tiles 2..31; each COMP's tile landed at the preceding WAITVM(4).
    for (int kk = 0; kk < NT - 2; kk += 3) {
        COMP(0); BARRIER(); STAGE(2, kk + 2); WAITVM(4); SCHEDB(); BARRIER();
        COMP(1); BARRIER(); STAGE(0, kk + 3); WAITVM(4); SCHEDB(); BARRIER();
        COMP(2); BARRIER(); STAGE(1, kk + 4); WAITVM(4); SCHEDB(); BARRIER();
    }
    // drain: tile 30 (buf 0) landed at last WAITVM(4); tile 31 (buf 1) via vmcnt(0)
    COMP(0); WAITVM(0); SCHEDB(); BARRIER();
    COMP(1);
    BARRIER();                       // all LDS reads done -> Cs overlay safe

#undef STAGE
#undef COMP

    // ---- epilogue: two column-half rounds through a 128x64 f32 LDS transpose
    // (XOR-swizzled quads), then full-line float4 writes / RMW ----
    // C/D fragment layout: row = wr + i*16 + q4*4 + rg, col = wcc + j*16 + m16
#pragma unroll
    for (int r = 0; r < 2; ++r) {
        if ((w & 1) == r) {          // waves owning cols [r*64, r*64+64)
#pragma unroll
            for (int j = 0; j < 4; ++j) {
#pragma unroll
                for (int i = 0; i < 4; ++i) {
#pragma unroll
                    for (int rg = 0; rg < 4; ++rg) {
                        int rl = wr + i * 16 + q4 * 4 + rg;    // 0..127
                        int cl = j * 16 + m16;                  // 0..63 local
                        int cq = (cl >> 2) ^ (rl & 15);         // swizzled quad
                        Cs[rl * 64 + cq * 4 + (cl & 3)] = acc[i][j][rg];
                    }
                }
            }
        }
        BARRIER();
        // reader: 4 lanes/row, two row-halves per thread -> all 128 rows
#pragma unroll
        for (int rh = 0; rh < 2; ++rh) {
            int rr = w * 32 + rh * 16 + (lane >> 2);
            int gr2 = row0 + rr;
            if (gr2 < n_e) {
                int tok = s_tok[rr];
                float wgt = s_w[rr];
                float* orow = out + (size_t)tok * DF + col0 + r * 64;
                const float* brow = be + e * DF + col0 + r * 64;
#pragma unroll
                for (int kq = 0; kq < 4; ++kq) {
                    int cq_log = kq * 4 + (lane & 3);      // logical quad 0..15
                    int c4 = cq_log * 4;
                    floatx4 v  = *(const floatx4*)&Cs[rr * 64 + ((cq_log ^ (rr & 15)) * 4)];
                    floatx4 bv = *(const floatx4*)&brow[c4];
                    floatx4 rv;
#pragma unroll
                    for (int z = 0; z < 4; ++z) rv[z] = wgt * (v[z] + bv[z]);
                    if (ACC) {
                        floatx4 o = *(const floatx4*)&orow[c4];
#pragma unroll
                        for (int z = 0; z < 4; ++z) rv[z] += o[z];
                    }
                    *(floatx4*)&orow[c4] = rv;
                }
            }
        }
        BARRIER();                   // round-0 reads done before round-1 rewrites Cs
    }
}

extern "C" void kernel_launch(void* const* d_in, const int* in_sizes, int n_in,
                              void* d_out, int out_size, void* d_ws, size_t ws_size,
                              hipStream_t stream) {
    const float* x  = (const float*)d_in[0];
    const float* Wg = (const float*)d_in[1];
    const float* bg = (const float*)d_in[2];
    const float* We = (const float*)d_in[3];
    const float* be = (const float*)d_in[4];
    float* out = (float*)d_out;

    int T = in_sizes[0] / DM;
    int n_slots = 2 * T;
    int NB = (n_slots + 255) / 256;

    char* ws = (char*)d_ws;
    size_t xb_bytes  = (size_t)T * DM * 2;
    size_t weT_bytes = (size_t)NE * DM * DF * 2;
    __bf16* Xb  = (__bf16*)ws;
    __bf16* WeT = (__bf16*)(ws + xb_bytes);
    char* rt = ws + xb_bytes + weT_bytes;
    int*   ntiles    = (int*)(rt + 0);
    int4*  wl        = (int4*)(rt + 64);                     // 2 * 136 int4
    int*   blk_cnt   = (int*)(rt + 64 + 2 * MAXT * 16);
    int*   blk_base  = (int*)((char*)blk_cnt + (size_t)NB * NBIN * 4);
    int*   tok_e     = (int*)((char*)blk_base + (size_t)NB * NBIN * 4);
    float* tok_w     = (float*)((char*)tok_e + (size_t)n_slots * 4);
    int*   gath_tok  = (int*)((char*)tok_w + (size_t)n_slots * 4);
    float* gath_w    = (float*)((char*)gath_tok + (size_t)n_slots * 4);

    convert_weT<<<dim3(DF / 256, DM / 8, NE), 256, 0, stream>>>(We, WeT);
    gate_kernel<<<(T + 3) / 4, 256, 0, stream>>>((const float4*)x, (const float4*)Wg,
                                                 bg, tok_e, tok_w, Xb, T);
    hist_kernel<<<NB, 256, 0, stream>>>(tok_e, blk_cnt, n_slots);
    scan_kernel<<<1, 256, 0, stream>>>(blk_cnt, blk_base, wl, ntiles, NB);
    scatter_kernel<<<NB, 256, 0, stream>>>(tok_e, tok_w, blk_base, gath_tok, gath_w, n_slots);

    expert_gemm_mfma<false><<<MAXT * 8, 256, 0, stream>>>(Xb, WeT, be, wl, ntiles,
                                                          gath_tok, gath_w, out);
    expert_gemm_mfma<true><<<MAXT * 8, 256, 0, stream>>>(Xb, WeT, be, wl + MAXT, ntiles + 1,
                                                         gath_tok, gath_w, out);
}